// Round 14
// baseline (961.661 us; speedup 1.0000x reference)
//
#include <hip/hip_runtime.h>
#include <hip/hip_fp16.h>
#include <stdint.h>

#define NUM_TOTAL 150000
#define NUM_USER  50000
#define NUM_ITEM  100000
#define E_SOC 1600000
#define E_CO  3200000
#define BATCH 512
#define MAX_UI 64
#define MAX_IU 50
#define NWALK 96
#define NCAND 11
#define NB    586    // ceil(150000/256) coarse dst-buckets (256 nodes each)
#define NWG   192    // partition workgroups (= 64 lanes x 3 for wave scan)
// ---- top-k filter parameters ----
#define PARTS 4
#define PIT   25000            // items per part (100000/4)
#define PMW   784              // ceil(25000/32) padded
#define SCAP  192              // survivor capacity per (row,part); lambda ~= 32
#define TH    8377900u         // v threshold: P(v>=TH) ~= 1.28e-3 -> ~128 survivors/row
// ---- negA-into-agg_co interleave ----
#define AGGGRID 37500          // (NUM_TOTAL+3)/4
#define NEGPER  1024           // negA blocks per fused dispatch (2 dispatches x 1024 = 2048)
#define ILP_P   37             // interleave period (1 negA block every 37)

// ---------------- threefry2x32, key = (0, 42) ----------------
__device__ __forceinline__ uint32_t rotl32(uint32_t x, int r){ return (x<<r)|(x>>(32-r)); }

__device__ __forceinline__ void tf_core(uint32_t x0, uint32_t x1, uint32_t& o0, uint32_t& o1){
  const uint32_t k0 = 0u, k1 = 42u, k2 = 0u ^ 42u ^ 0x1BD11BDAu;
  x0 += k0; x1 += k1;
#define TF_R4(a,b,c,d) \
  x0+=x1; x1=rotl32(x1,a); x1^=x0; \
  x0+=x1; x1=rotl32(x1,b); x1^=x0; \
  x0+=x1; x1=rotl32(x1,c); x1^=x0; \
  x0+=x1; x1=rotl32(x1,d); x1^=x0;
  TF_R4(13,15,26,6)   x0+=k1; x1+=k2+1u;
  TF_R4(17,29,16,24)  x0+=k2; x1+=k0+2u;
  TF_R4(13,15,26,6)   x0+=k0; x1+=k1+3u;
  TF_R4(17,29,16,24)  x0+=k1; x1+=k2+4u;
  TF_R4(13,15,26,6)   x0+=k2; x1+=k0+5u;
#undef TF_R4
  o0 = x0; o1 = x1;
}

__device__ __forceinline__ uint32_t tf_bits(uint32_t j){
  uint32_t o0, o1;
  tf_core(0u, j, o0, o1);
  return o0 ^ o1;
}

// ---------------- pass 1: per-WG bucket counts, BOTH graphs ----------------
// cntMat layout is TRANSPOSED: [NB][NWG] so a wave per bucket can scan it.
__global__ __launch_bounds__(256) void pcountB_k(const int* __restrict__ socDst,
                                                 const int* __restrict__ coDst,
                                                 int chunkS, int chunkC,
                                                 int* __restrict__ cntMatS,
                                                 int* __restrict__ cntMatC){
  __shared__ int h[NB];
  int tid = threadIdx.x;
  bool isSoc = blockIdx.x < NWG;
  int wg = isSoc ? blockIdx.x : blockIdx.x - NWG;
  const int* dst = isSoc ? socDst : coDst;
  int E = isSoc ? E_SOC : E_CO;
  int chunk = isSoc ? chunkS : chunkC;
  int* cntMat = isSoc ? cntMatS : cntMatC;
  for (int i=tid; i<NB; i+=256) h[i]=0;
  __syncthreads();
  int lo = wg*chunk, hi = lo+chunk; if (hi > E) hi = E;
  for (int i=lo+tid; i<hi; i+=256) atomicAdd(&h[dst[i]>>8], 1);
  __syncthreads();
  for (int i=tid; i<NB; i+=256) cntMat[(size_t)i*NWG + wg] = h[i];
}

// ---------------- bucket totals: wave per bucket, both graphs ----------------
__global__ void btot2_k(const int* __restrict__ cntMatS, const int* __restrict__ cntMatC,
                        int* __restrict__ totS, int* __restrict__ totC){
  int g = (blockIdx.x*blockDim.x + threadIdx.x) >> 6;
  int lane = threadIdx.x & 63;
  if (g >= 2*NB) return;
  bool isSoc = g < NB;
  int b = isSoc ? g : g - NB;
  const int* row = (isSoc ? cntMatS : cntMatC) + (size_t)b*NWG;
  int s = row[lane*3] + row[lane*3+1] + row[lane*3+2];
  #pragma unroll
  for (int d=32; d; d>>=1) s += __shfl_xor(s, d, 64);
  if (lane == 0) (isSoc ? totS : totC)[b] = s;
}

// ---------------- scan bucket totals -> bbase (1 block per graph) ----------------
__global__ __launch_bounds__(1024) void bscan2_k(const int* __restrict__ totS, const int* __restrict__ totC,
                                                 int* __restrict__ bbaseS, int* __restrict__ bbaseC){
  __shared__ int sa[1024];
  int tid = threadIdx.x;
  const int* tot = blockIdx.x ? totC : totS;
  int* bbase     = blockIdx.x ? bbaseC : bbaseS;
  int E          = blockIdx.x ? E_CO   : E_SOC;
  int v = (tid < NB) ? tot[tid] : 0;
  sa[tid] = v;
  __syncthreads();
  for (int s=1; s<1024; s<<=1){
    int t = (tid>=s)?sa[tid-s]:0;
    __syncthreads();
    sa[tid] += t;
    __syncthreads();
  }
  if (tid < NB) bbase[tid] = sa[tid] - v;   // exclusive
  if (tid == 0) bbase[NB] = E;
}

// ---------------- per-(bucket,wg) start offsets: wave per bucket (shfl scan) ----------------
__global__ void wgpfx2_k(int* __restrict__ cntMatS, int* __restrict__ cntMatC,
                         const int* __restrict__ bbaseS, const int* __restrict__ bbaseC){
  int g = (blockIdx.x*blockDim.x + threadIdx.x) >> 6;
  int lane = threadIdx.x & 63;
  if (g >= 2*NB) return;
  bool isSoc = g < NB;
  int b = isSoc ? g : g - NB;
  int* row = (isSoc ? cntMatS : cntMatC) + (size_t)b*NWG;
  int base = (isSoc ? bbaseS : bbaseC)[b];
  int v0 = row[lane*3], v1 = row[lane*3+1], v2 = row[lane*3+2];
  int s = v0 + v1 + v2;
  int x = s;
  #pragma unroll
  for (int d=1; d<64; d<<=1){
    int t = __shfl_up(x, d, 64);
    if (lane >= d) x += t;
  }
  int excl = x - s;    // exclusive prefix of lane partials
  row[lane*3]   = base + excl;
  row[lane*3+1] = base + excl + v0;
  row[lane*3+2] = base + excl + v0 + v1;
}

// ---------------- pass 2: place records (LDS cursors, WG-private), both graphs ----------------
// soc record: u64 = (w_bits<<32) | (d_local<<18) | s ; co record: u32 = (d_local<<18) | s
__global__ __launch_bounds__(256) void pplaceB_k(const int* __restrict__ socSrc,
        const int* __restrict__ socDst, const float* __restrict__ socWgt,
        const int* __restrict__ coSrc,  const int* __restrict__ coDst,
        const int* __restrict__ cntMatS, const int* __restrict__ cntMatC,
        unsigned long long* __restrict__ recS, unsigned int* __restrict__ recC,
        int chunkS, int chunkC){
  __shared__ int curx[NB];
  int tid = threadIdx.x;
  bool isSoc = blockIdx.x < NWG;
  int wg = isSoc ? blockIdx.x : blockIdx.x - NWG;
  const int* offMat = isSoc ? cntMatS : cntMatC;
  for (int i=tid; i<NB; i+=256) curx[i] = offMat[(size_t)i*NWG + wg];
  __syncthreads();
  if (isSoc){
    int lo = wg*chunkS, hi = lo+chunkS; if (hi > E_SOC) hi = E_SOC;
    for (int i=lo+tid; i<hi; i+=256){
      int d = socDst[i];
      int p = atomicAdd(&curx[d>>8], 1);
      recS[p] = ((unsigned long long)__float_as_uint(socWgt[i])<<32)
              | (unsigned)(((d&255)<<18) | socSrc[i]);
    }
  } else {
    int lo = wg*chunkC, hi = lo+chunkC; if (hi > E_CO) hi = E_CO;
    for (int i=lo+tid; i<hi; i+=256){
      int d = coDst[i];
      int p = atomicAdd(&curx[d>>8], 1);
      recC[p] = (unsigned)(((d&255)<<18) | coSrc[i]);
    }
  }
}

// ---------------- bucket -> CSC, both graphs; folds alpha softmax (soc) and dinv (co) ----------------
__global__ __launch_bounds__(256) void cscB_k(const unsigned long long* __restrict__ recS,
    const unsigned int* __restrict__ recC,
    const int* __restrict__ bbaseS, const int* __restrict__ bbaseC,
    int* __restrict__ socOff, int* __restrict__ socSrcS, float* __restrict__ socWS,
    int* __restrict__ coOff, int* __restrict__ coSrcS, float* __restrict__ dinv){
  __shared__ int cnt[256], basex[256], curx[256];
  int tid = threadIdx.x;
  bool isSoc = blockIdx.x < NB;
  int b = isSoc ? blockIdx.x : blockIdx.x - NB;
  const int* bbase = isSoc ? bbaseS : bbaseC;
  int lo = bbase[b], hi = bbase[b+1];
  cnt[tid] = 0;
  __syncthreads();
  if (isSoc){
    for (int i = lo + tid; i < hi; i += 256)
      atomicAdd(&cnt[(((unsigned)recS[i]) >> 18) & 255], 1);
  } else {
    for (int i = lo + tid; i < hi; i += 256)
      atomicAdd(&cnt[(recC[i] >> 18) & 255], 1);
  }
  __syncthreads();
  int c = cnt[tid];
  basex[tid] = c; __syncthreads();
  for (int s=1; s<256; s<<=1){
    int t = (tid>=s)?basex[tid-s]:0; __syncthreads();
    basex[tid]+=t; __syncthreads();
  }
  int excl = basex[tid]-c;
  int node = b*256+tid;
  int* off = isSoc ? socOff : coOff;
  if (node <= NUM_TOTAL) off[node] = lo + excl;
  basex[tid] = excl; curx[tid] = 0;
  __syncthreads();
  if (isSoc){
    for (int i = lo + tid; i < hi; i += 256){
      unsigned long long r = recS[i];
      unsigned lw = (unsigned)r;
      int dl = (lw>>18)&255;
      int p = lo + basex[dl] + atomicAdd(&curx[dl],1);
      socSrcS[p] = lw & 0x3FFFF;
      socWS[p] = __uint_as_float((unsigned)(r>>32));
    }
    __syncthreads();
    // folded alpha softmax: this block owns ALL edges of its 256 nodes (L2-hot)
    if (node < NUM_TOTAL && c > 0){
      int e0 = lo + basex[tid], e1 = e0 + c;
      float m = -3.402823466e+38f;
      for (int e=e0; e<e1; ++e) m = fmaxf(m, socWS[e]);
      float s = 0.f;
      for (int e=e0; e<e1; ++e) s += expf(socWS[e] - m);
      float inv = 1.0f / (s + 1e-16f);
      for (int e=e0; e<e1; ++e) socWS[e] = expf(socWS[e] - m) * inv;
    }
  } else {
    for (int i = lo + tid; i < hi; i += 256){
      unsigned r = recC[i];
      int dl = (r>>18)&255;
      int p = lo + basex[dl] + atomicAdd(&curx[dl],1);
      coSrcS[p] = r & 0x3FFFF;
    }
    // folded dinv (deg = in-degree + self loop)
    if (node < NUM_TOTAL) dinv[node] = 1.0f / sqrtf((float)(c + 1));
  }
}

// f32 -> f16, both tables in one pass (float4 in, 8B out)
__global__ void f2h2_k(const float4* __restrict__ a, uint2* __restrict__ oa,
                       const float4* __restrict__ b, uint2* __restrict__ ob, int n4){
  int i = blockIdx.x*blockDim.x+threadIdx.x, st = gridDim.x*blockDim.x;
  for (; i<n4; i+=st){
    float4 va = a[i], vb = b[i];
    __half2 l = __float22half2_rn(make_float2(va.x,va.y));
    __half2 h = __float22half2_rn(make_float2(va.z,va.w));
    uint2 u; u.x = *(unsigned*)&l; u.y = *(unsigned*)&h;
    oa[i] = u;
    l = __float22half2_rn(make_float2(vb.x,vb.y));
    h = __float22half2_rn(make_float2(vb.z,vb.w));
    u.x = *(unsigned*)&l; u.y = *(unsigned*)&h;
    ob[i] = u;
  }
}

// ---------------- soc aggregation: wave per dst node, f16 rows, 8-way MLP ----------------
__global__ void agg_soc8_k(const __half2* __restrict__ x, __half2* __restrict__ y,
                           const int* __restrict__ off, const int* __restrict__ srcS,
                           const float* __restrict__ wE, int n){
  int gw = (blockIdx.x*blockDim.x + threadIdx.x) >> 6;
  int lane = threadIdx.x & 63;
  if (gw >= n) return;
  float ax = 0.f, ay = 0.f;
  int e = off[gw], e1 = off[gw+1];
  for (; e + 8 <= e1; e += 8){
    int s0=srcS[e],s1=srcS[e+1],s2=srcS[e+2],s3=srcS[e+3];
    int s4=srcS[e+4],s5=srcS[e+5],s6=srcS[e+6],s7=srcS[e+7];
    float a0=wE[e],a1=wE[e+1],a2=wE[e+2],a3=wE[e+3];
    float a4=wE[e+4],a5=wE[e+5],a6=wE[e+6],a7=wE[e+7];
    __half2 h0=x[(size_t)s0*64+lane], h1=x[(size_t)s1*64+lane];
    __half2 h2=x[(size_t)s2*64+lane], h3=x[(size_t)s3*64+lane];
    __half2 h4=x[(size_t)s4*64+lane], h5=x[(size_t)s5*64+lane];
    __half2 h6=x[(size_t)s6*64+lane], h7=x[(size_t)s7*64+lane];
    float2 f0=__half22float2(h0), f1=__half22float2(h1), f2=__half22float2(h2), f3=__half22float2(h3);
    float2 f4=__half22float2(h4), f5=__half22float2(h5), f6=__half22float2(h6), f7=__half22float2(h7);
    ax += a0*f0.x + a1*f1.x + a2*f2.x + a3*f3.x + a4*f4.x + a5*f5.x + a6*f6.x + a7*f7.x;
    ay += a0*f0.y + a1*f1.y + a2*f2.y + a3*f3.y + a4*f4.y + a5*f5.y + a6*f6.y + a7*f7.y;
  }
  for (; e < e1; ++e){
    int s = srcS[e]; float a = wE[e];
    float2 f = __half22float2(x[(size_t)s*64 + lane]);
    ax += a*f.x; ay += a*f.y;
  }
  y[(size_t)gw*64 + lane] = __float22half2_rn(make_float2(ax, ay));
}

// ---------------- fused: co aggregation (memory-bound) + interleaved negA blocks (VALU-bound) ----
// 1 negA block every ILP_P blocks -> co-resident throughout the dispatch, filling agg's
// idle VALU slots. negA touches no gather table (round-7 dual-working-set hazard absent).
__global__ __launch_bounds__(256) void aggco_negA_k(const __half2* __restrict__ x, __half2* __restrict__ y,
                          const int* __restrict__ off, const int* __restrict__ srcS,
                          const float* __restrict__ dinv,
                          const int* __restrict__ user_items,
                          unsigned long long* __restrict__ surv, int* __restrict__ scnt,
                          int negBase){
  __shared__ unsigned int mask[PMW];
  __shared__ int lcnt;
  int bid = blockIdx.x, tid = threadIdx.x;
  int q = bid / ILP_P;
  bool isNeg = (bid % ILP_P == 17) && (q < NEGPER);
  if (isNeg){
    // ---- negA body (verbatim; blk in [negBase, negBase+NEGPER)) ----
    int blk = negBase + q;
    int row = blk >> 2, part = blk & 3;
    int base = part * PIT;
    for (int i=tid; i<PMW; i+=256) mask[i] = 0u;
    if (tid == 0) lcnt = 0;
    __syncthreads();
    if (tid < MAX_UI){
      int it = user_items[row*MAX_UI + tid];
      if (it >= base && it < base + PIT){
        int li = it - base;
        atomicOr(&mask[li>>5], 1u << (li & 31));
      }
    }
    __syncthreads();
    unsigned jbase = (unsigned)row * 100000u + (unsigned)base;
    for (int k = tid; k < PIT; k += 1024){
      int i1 = k + 256, i2 = k + 512, i3 = k + 768;
      uint32_t b0 = tf_bits(jbase + (unsigned)k);
      uint32_t b1 = tf_bits(jbase + (unsigned)(i1 < PIT ? i1 : k));
      uint32_t b2 = tf_bits(jbase + (unsigned)(i2 < PIT ? i2 : k));
      uint32_t b3 = tf_bits(jbase + (unsigned)(i3 < PIT ? i3 : k));
      uint32_t v0 = b0 >> 9, v1 = b1 >> 9, v2 = b2 >> 9, v3 = b3 >> 9;
      if (v0 >= TH && !((mask[k>>5] >> (k&31)) & 1u)){
        int p = atomicAdd(&lcnt, 1);
        if (p < SCAP)
          surv[(size_t)blk*SCAP + p] = ((unsigned long long)v0 << 32) | (unsigned)(~(unsigned)(base + k));
      }
      if (i1 < PIT && v1 >= TH && !((mask[i1>>5] >> (i1&31)) & 1u)){
        int p = atomicAdd(&lcnt, 1);
        if (p < SCAP)
          surv[(size_t)blk*SCAP + p] = ((unsigned long long)v1 << 32) | (unsigned)(~(unsigned)(base + i1));
      }
      if (i2 < PIT && v2 >= TH && !((mask[i2>>5] >> (i2&31)) & 1u)){
        int p = atomicAdd(&lcnt, 1);
        if (p < SCAP)
          surv[(size_t)blk*SCAP + p] = ((unsigned long long)v2 << 32) | (unsigned)(~(unsigned)(base + i2));
      }
      if (i3 < PIT && v3 >= TH && !((mask[i3>>5] >> (i3&31)) & 1u)){
        int p = atomicAdd(&lcnt, 1);
        if (p < SCAP)
          surv[(size_t)blk*SCAP + p] = ((unsigned long long)v3 << 32) | (unsigned)(~(unsigned)(base + i3));
      }
    }
    __syncthreads();
    if (tid == 0) scnt[blk] = (lcnt < SCAP) ? lcnt : SCAP;
  } else {
    // ---- agg_co body (verbatim, with remapped block index) ----
    int nneg = (bid > 17) ? min((bid - 18)/ILP_P + 1, NEGPER) : 0;
    int aggId = bid - nneg;
    int gw = aggId*4 + (tid >> 6);
    int lane = tid & 63;
    if (gw >= NUM_TOTAL) return;
    float dv = dinv[gw];
    float2 fs = __half22float2(x[(size_t)gw*64 + lane]);
    float ax = dv*dv*fs.x, ay = dv*dv*fs.y;    // self-loop
    int e = off[gw], e1 = off[gw+1];
    for (; e + 8 <= e1; e += 8){
      int s0=srcS[e],s1=srcS[e+1],s2=srcS[e+2],s3=srcS[e+3];
      int s4=srcS[e+4],s5=srcS[e+5],s6=srcS[e+6],s7=srcS[e+7];
      float a0=dinv[s0]*dv,a1=dinv[s1]*dv,a2=dinv[s2]*dv,a3=dinv[s3]*dv;
      float a4=dinv[s4]*dv,a5=dinv[s5]*dv,a6=dinv[s6]*dv,a7=dinv[s7]*dv;
      __half2 h0=x[(size_t)s0*64+lane], h1=x[(size_t)s1*64+lane];
      __half2 h2=x[(size_t)s2*64+lane], h3=x[(size_t)s3*64+lane];
      __half2 h4=x[(size_t)s4*64+lane], h5=x[(size_t)s5*64+lane];
      __half2 h6=x[(size_t)s6*64+lane], h7=x[(size_t)s7*64+lane];
      float2 f0=__half22float2(h0), f1=__half22float2(h1), f2=__half22float2(h2), f3=__half22float2(h3);
      float2 f4=__half22float2(h4), f5=__half22float2(h5), f6=__half22float2(h6), f7=__half22float2(h7);
      ax += a0*f0.x + a1*f1.x + a2*f2.x + a3*f3.x + a4*f4.x + a5*f5.x + a6*f6.x + a7*f7.x;
      ay += a0*f0.y + a1*f1.y + a2*f2.y + a3*f3.y + a4*f4.y + a5*f5.y + a6*f6.y + a7*f7.y;
    }
    for (; e < e1; ++e){
      int s = srcS[e]; float a = dinv[s]*dv;
      float2 f = __half22float2(x[(size_t)s*64 + lane]);
      ax += a*f.x; ay += a*f.y;
    }
    y[(size_t)gw*64 + lane] = __float22half2_rn(make_float2(ax, ay));
  }
}

// L2-normalize f16 rows in place (wave per row)
__global__ void norm_h_k(__half2* __restrict__ x, int n){
  int gw = (blockIdx.x*blockDim.x + threadIdx.x) >> 6;
  int lane = threadIdx.x & 63;
  if (gw >= n) return;
  __half2* p = x + (size_t)gw*64;
  float2 v = __half22float2(p[lane]);
  float ss = v.x*v.x + v.y*v.y;
  #pragma unroll
  for (int s=32; s; s>>=1) ss += __shfl_xor(ss, s, 64);
  float sc = 1.0f / fmaxf(sqrtf(ss), 1e-12f);
  p[lane] = __float22half2_rn(make_float2(v.x*sc, v.y*sc));
}

// fused: co-norm (150K waves) + anchor build+norm (100K waves) — 10-way static MLP
__global__ void postA_k(__half2* __restrict__ coE, const __half2* __restrict__ socE,
                        const int* __restrict__ item_users, __half2* __restrict__ anch){
  int gw = (blockIdx.x*blockDim.x + threadIdx.x) >> 6;
  int lane = threadIdx.x & 63;
  if (gw < NUM_TOTAL){
    __half2* p = coE + (size_t)gw*64;
    float2 v = __half22float2(p[lane]);
    float ss = v.x*v.x + v.y*v.y;
    #pragma unroll
    for (int s=32; s; s>>=1) ss += __shfl_xor(ss, s, 64);
    float sc = 1.0f / fmaxf(sqrtf(ss), 1e-12f);
    p[lane] = __float22half2_rn(make_float2(v.x*sc, v.y*sc));
  } else {
    int it = gw - NUM_TOTAL;
    if (it >= NUM_ITEM) return;
    const int* us = item_users + (size_t)it*MAX_IU;
    float ax = 0.f, ay = 0.f;
    for (int k=0; k<MAX_IU; k+=10){
      int u0=us[k],u1=us[k+1],u2=us[k+2],u3=us[k+3],u4=us[k+4];
      int u5=us[k+5],u6=us[k+6],u7=us[k+7],u8=us[k+8],u9=us[k+9];
      __half2 h0=socE[(size_t)u0*64+lane], h1=socE[(size_t)u1*64+lane];
      __half2 h2=socE[(size_t)u2*64+lane], h3=socE[(size_t)u3*64+lane];
      __half2 h4=socE[(size_t)u4*64+lane], h5=socE[(size_t)u5*64+lane];
      __half2 h6=socE[(size_t)u6*64+lane], h7=socE[(size_t)u7*64+lane];
      __half2 h8=socE[(size_t)u8*64+lane], h9=socE[(size_t)u9*64+lane];
      float2 f0=__half22float2(h0), f1=__half22float2(h1), f2=__half22float2(h2);
      float2 f3=__half22float2(h3), f4=__half22float2(h4), f5=__half22float2(h5);
      float2 f6=__half22float2(h6), f7=__half22float2(h7), f8=__half22float2(h8);
      float2 f9=__half22float2(h9);
      ax += f0.x+f1.x+f2.x+f3.x+f4.x+f5.x+f6.x+f7.x+f8.x+f9.x;
      ay += f0.y+f1.y+f2.y+f3.y+f4.y+f5.y+f6.y+f7.y+f8.y+f9.y;
    }
    const float inv = 1.0f / (50.0f + 1e-7f);
    ax *= inv; ay *= inv;
    float ss = ax*ax + ay*ay;
    #pragma unroll
    for (int s=32; s; s>>=1) ss += __shfl_xor(ss, s, 64);
    float sc = 1.0f / fmaxf(sqrtf(ss), 1e-12f);
    anch[(size_t)it*64 + lane] = __float22half2_rn(make_float2(ax*sc, ay*sc));
  }
}

// ---------------- negatives: phase B — merge survivors, exact top-10 ----------------
__global__ __launch_bounds__(256) void negB_k(const unsigned long long* __restrict__ surv,
                                              const int* __restrict__ scnt,
                                              const int* __restrict__ user_items,
                                              const int* __restrict__ n_id,
                                              int* __restrict__ cand){
  __shared__ unsigned long long keys[PARTS*SCAP];
  __shared__ unsigned long long red[256];
  __shared__ int cnts[PARTS];
  __shared__ int uix[MAX_UI];
  int b = blockIdx.x, tid = threadIdx.x;
  if (tid < PARTS) cnts[tid] = scnt[b*PARTS + tid];
  for (int i=tid; i<PARTS*SCAP; i+=256) keys[i] = 0ull;
  __syncthreads();
  int o0 = 0, o1 = cnts[0], o2 = o1 + cnts[1], o3 = o2 + cnts[2];
  int total = o3 + cnts[3];
  if (tid < cnts[0]) keys[o0 + tid] = surv[(size_t)(b*PARTS+0)*SCAP + tid];
  if (tid < cnts[1]) keys[o1 + tid] = surv[(size_t)(b*PARTS+1)*SCAP + tid];
  if (tid < cnts[2]) keys[o2 + tid] = surv[(size_t)(b*PARTS+2)*SCAP + tid];
  if (tid < cnts[3]) keys[o3 + tid] = surv[(size_t)(b*PARTS+3)*SCAP + tid];
  __syncthreads();
  if (total >= 10){
    for (int r=0; r<10; ++r){
      unsigned long long m = 0ull;
      for (int i=tid; i<PARTS*SCAP; i+=256){ unsigned long long v = keys[i]; if (v > m) m = v; }
      red[tid] = m; __syncthreads();
      for (int s=128; s>0; s>>=1){
        if (tid < s && red[tid+s] > red[tid]) red[tid] = red[tid+s];
        __syncthreads();
      }
      unsigned long long win = red[0];
      if (tid == 0)
        cand[b*NCAND + 1 + r] = NUM_USER + (int)(~(unsigned)(win & 0xffffffffull));
      for (int i=tid; i<PARTS*SCAP; i+=256) if (keys[i] == win) keys[i] = 0ull;
      __syncthreads();
    }
  } else {
    // deterministic exact slow path (probability ~e^-100; never taken in practice)
    if (tid < MAX_UI) uix[tid] = user_items[b*MAX_UI + tid];
    __syncthreads();
    unsigned long long prev = ~0ull;
    for (int r=0; r<10; ++r){
      unsigned long long m = 0ull;
      for (int i=tid; i<NUM_ITEM; i+=256){
        bool msk = false;
        for (int j=0; j<MAX_UI; ++j) if (uix[j] == i) msk = true;
        if (msk) continue;
        uint32_t v = tf_bits((unsigned)b*100000u + (unsigned)i) >> 9;
        unsigned long long key = ((unsigned long long)v << 32) | (unsigned)(~(unsigned)i);
        if (key < prev && key > m) m = key;
      }
      red[tid] = m; __syncthreads();
      for (int s=128; s>0; s>>=1){
        if (tid < s && red[tid+s] > red[tid]) red[tid] = red[tid+s];
        __syncthreads();
      }
      unsigned long long win = red[0];
      prev = win;
      if (tid == 0)
        cand[b*NCAND + 1 + r] = NUM_USER + (int)(~(unsigned)(win & 0xffffffffull));
      __syncthreads();
    }
  }
  if (tid == 0) cand[b*NCAND] = n_id[b*2 + 1];   // positive item (global id)
}

// ---------------- similarity (mean over walks collapses to one dot), f16 rows ----------------
__global__ void sim_h_k(const __half2* __restrict__ coN, const __half2* __restrict__ socU,
                        const __half2* __restrict__ socI, const int* __restrict__ cand,
                        const int* __restrict__ walks, float* __restrict__ out){
  int b = blockIdx.x;
  int lane = threadIdx.x;   // 64 threads
  float scx=0.f, scy=0.f, ssx=0.f, ssy=0.f;
  for (int w=0; w<NWALK; w+=4){
    int i0 = walks[b*NWALK + w],   i1 = walks[b*NWALK + w+1];
    int i2 = walks[b*NWALK + w+2], i3 = walks[b*NWALK + w+3];
    __half2 c0 = coN[(size_t)i0*64 + lane], c1 = coN[(size_t)i1*64 + lane];
    __half2 c2 = coN[(size_t)i2*64 + lane], c3 = coN[(size_t)i3*64 + lane];
    const __half2* p0 = (i0 < NUM_USER) ? socU + (size_t)i0*64 : socI + (size_t)(i0-NUM_USER)*64;
    const __half2* p1 = (i1 < NUM_USER) ? socU + (size_t)i1*64 : socI + (size_t)(i1-NUM_USER)*64;
    const __half2* p2 = (i2 < NUM_USER) ? socU + (size_t)i2*64 : socI + (size_t)(i2-NUM_USER)*64;
    const __half2* p3 = (i3 < NUM_USER) ? socU + (size_t)i3*64 : socI + (size_t)(i3-NUM_USER)*64;
    __half2 s0 = p0[lane], s1 = p1[lane], s2 = p2[lane], s3 = p3[lane];
    float2 fc0 = __half22float2(c0), fc1 = __half22float2(c1);
    float2 fc2 = __half22float2(c2), fc3 = __half22float2(c3);
    float2 fs0 = __half22float2(s0), fs1 = __half22float2(s1);
    float2 fs2 = __half22float2(s2), fs3 = __half22float2(s3);
    scx += fc0.x + fc1.x + fc2.x + fc3.x;
    scy += fc0.y + fc1.y + fc2.y + fc3.y;
    ssx += fs0.x + fs1.x + fs2.x + fs3.x;
    ssy += fs0.y + fs1.y + fs2.y + fs3.y;
  }
  for (int c=0; c<NCAND; ++c){
    int idx = cand[b*NCAND + c];                 // always in [NUM_USER, NUM_TOTAL)
    float2 cv = __half22float2(coN[(size_t)idx*64 + lane]);
    float2 sv = __half22float2(socI[(size_t)(idx - NUM_USER)*64 + lane]);
    float dco = cv.x*scx + cv.y*scy;
    float dso = sv.x*ssx + sv.y*ssy;
    #pragma unroll
    for (int s=32; s; s>>=1){
      dco += __shfl_xor(dco, s, 64);
      dso += __shfl_xor(dso, s, 64);
    }
    if (lane == 0){
      float com = 0.5f + 0.5f*(dco / 96.0f);
      float som = 0.5f + 0.5f*(dso / 96.0f);
      out[b*NCAND + c] = 0.7f*com + 0.3f*som;
    }
  }
}

// ---------------- host ----------------
extern "C" void kernel_launch(void* const* d_in, const int* in_sizes, int n_in,
                              void* d_out, int out_size, void* d_ws, size_t ws_size,
                              hipStream_t stream){
  (void)in_sizes; (void)n_in; (void)out_size; (void)ws_size;
  const float* id_emb     = (const float*)d_in[0];
  const float* soc_id_emb = (const float*)d_in[1];
  const float* soc_w      = (const float*)d_in[2];
  const int*   soc_ei     = (const int*)d_in[3];   // [0:E) src, [E:2E) dst
  const int*   co_ei      = (const int*)d_in[4];
  const int*   n_id       = (const int*)d_in[5];
  const int*   user_items = (const int*)d_in[6];
  const int*   item_users = (const int*)d_in[7];
  const int*   walks      = (const int*)d_in[8];
  float* out = (float*)d_out;

  // workspace layout (~225 MB; records aliased into t16, anchors into socId16)
  char* w = (char*)d_ws;
  size_t cur = 0;
  auto take = [&](size_t bytes)->void*{
    void* p = w + cur;
    cur = (cur + bytes + 255) & ~(size_t)255;
    return p;
  };
  __half2* socId16 = (__half2*)take((size_t)NUM_TOTAL*64*4);   // f16 soc_id_emb; later reused as anch16
  __half2* id16    = (__half2*)take((size_t)NUM_TOTAL*64*4);   // f16 id_emb; layer-2 co output
  __half2* t16     = (__half2*)take((size_t)NUM_TOTAL*64*4);   // rec buffers now, layer-2 soc output later
  __half2* soc16   = (__half2*)take((size_t)NUM_TOTAL*64*4);   // layer-1 soc output
  __half2* co16    = (__half2*)take((size_t)NUM_TOTAL*64*4);   // layer-1 co output
  int*   socOff  = (int*)take((size_t)(NUM_TOTAL+1)*4);
  int*   coOff   = (int*)take((size_t)(NUM_TOTAL+1)*4);
  float* dinv    = (float*)take((size_t)NUM_TOTAL*4);
  int*   socSrcS = (int*)take((size_t)E_SOC*4);
  float* socWS   = (float*)take((size_t)E_SOC*4);
  int*   coSrcS  = (int*)take((size_t)E_CO*4);
  int*   cntMatS = (int*)take((size_t)NWG*NB*4);   // layout [NB][NWG]
  int*   cntMatC = (int*)take((size_t)NWG*NB*4);   // layout [NB][NWG]
  int*   bbaseS  = (int*)take((size_t)(NB+1)*4);
  int*   bbaseC  = (int*)take((size_t)(NB+1)*4);
  int*   totS    = (int*)take((size_t)NB*4);
  int*   totC    = (int*)take((size_t)NB*4);
  unsigned long long* surv = (unsigned long long*)take((size_t)BATCH*PARTS*SCAP*8);
  int*   scnt    = (int*)take((size_t)BATCH*PARTS*4);
  int*   cand    = (int*)take((size_t)BATCH*NCAND*4);

  // records aliased into t16's 38.4 MB (dead until layer-2 agg writes t16):
  unsigned long long* recS = (unsigned long long*)t16;                        // 12.8 MB
  unsigned int*       recC = (unsigned int*)((char*)t16 + (size_t)E_SOC*8);   // 12.8 MB

  __half2* anch16 = socId16;   // socId16 dead after layer-1 agg

  const int T = 256;
  const int chunkS = (E_SOC + NWG - 1) / NWG;   // 8334
  const int chunkC = (E_CO  + NWG - 1) / NWG;   // 16667

  // ---- CSC build: contention-free two-pass counting partition (both graphs fused) ----
  pcountB_k<<<2*NWG, T, 0, stream>>>(soc_ei + E_SOC, co_ei + E_CO, chunkS, chunkC, cntMatS, cntMatC);
  int scanGrid = (2*NB*64 + T - 1) / T;   // wave per bucket
  btot2_k<<<scanGrid, T, 0, stream>>>(cntMatS, cntMatC, totS, totC);
  bscan2_k<<<2, 1024, 0, stream>>>(totS, totC, bbaseS, bbaseC);
  wgpfx2_k<<<scanGrid, T, 0, stream>>>(cntMatS, cntMatC, bbaseS, bbaseC);
  pplaceB_k<<<2*NWG, T, 0, stream>>>(soc_ei, soc_ei + E_SOC, soc_w,
                                     co_ei, co_ei + E_CO,
                                     cntMatS, cntMatC, recS, recC, chunkS, chunkC);
  cscB_k<<<2*NB, T, 0, stream>>>(recS, recC, bbaseS, bbaseC,
                                 socOff, socSrcS, socWS, coOff, coSrcS, dinv);

  // ---- f32 -> f16 embedding tables (stream-bound, must precede aggs) ----
  f2h2_k<<<2048, T, 0, stream>>>((const float4*)soc_id_emb, (uint2*)socId16,
                                 (const float4*)id_emb,     (uint2*)id16, NUM_TOTAL*32);

  // ---- graph convolutions; negA's VALU work interleaved into the two co dispatches ----
  int aggGrid = (NUM_TOTAL + 3) / 4;   // = AGGGRID
  agg_soc8_k<<<aggGrid, T, 0, stream>>>(socId16, soc16, socOff, socSrcS, socWS, NUM_TOTAL); // soc layer1
  aggco_negA_k<<<AGGGRID + NEGPER, T, 0, stream>>>(id16, co16, coOff, coSrcS, dinv,
                                                   user_items, surv, scnt, 0);              // co layer1 + negA[0:1024)
  agg_soc8_k<<<aggGrid, T, 0, stream>>>(soc16, t16, socOff, socSrcS, socWS, NUM_TOTAL);     // soc layer2 (recs dead)
  aggco_negA_k<<<AGGGRID + NEGPER, T, 0, stream>>>(co16, id16, coOff, coSrcS, dinv,
                                                   user_items, surv, scnt, NEGPER);         // co layer2 + negA[1024:2048)

  // final locations: soc_emb = t16, co_emb = id16
  __half2* socE = t16;
  __half2* coE  = id16;

  // ---- fused co-norm + anchors (anchor reads UNnormalized soc rows) ----
  postA_k<<<(2*NUM_TOTAL - NUM_USER + 3)/4, T, 0, stream>>>(coE, socE, item_users, anch16);
  norm_h_k<<<(NUM_USER + 3)/4, T, 0, stream>>>(socE, NUM_USER);   // soc_n users

  // ---- negatives phase B + final similarity ----
  negB_k<<<BATCH, T, 0, stream>>>(surv, scnt, user_items, n_id, cand);
  sim_h_k<<<BATCH, 64, 0, stream>>>(coE, socE, anch16, cand, walks, out);
}

// Round 15
// 949.995 us; speedup vs baseline: 1.0123x; 1.0123x over previous
//
#include <hip/hip_runtime.h>
#include <hip/hip_fp16.h>
#include <stdint.h>

#define NUM_TOTAL 150000
#define NUM_USER  50000
#define NUM_ITEM  100000
#define E_SOC 1600000
#define E_CO  3200000
#define BATCH 512
#define MAX_UI 64
#define MAX_IU 50
#define NWALK 96
#define NCAND 11
#define NB    586    // ceil(150000/256) coarse dst-buckets (256 nodes each)
#define NWG   192    // partition workgroups (= 64 lanes x 3 for wave scan)
// ---- top-k filter parameters ----
#define PARTS 4
#define PIT   25000            // items per part (100000/4)
#define PMW   784              // ceil(25000/32) padded
#define SCAP  192              // survivor capacity per (row,part); lambda ~= 32
#define TH    8377900u         // v threshold: P(v>=TH) ~= 1.28e-3 -> ~128 survivors/row

// ---------------- threefry2x32, key = (0, 42) ----------------
__device__ __forceinline__ uint32_t rotl32(uint32_t x, int r){ return (x<<r)|(x>>(32-r)); }

__device__ __forceinline__ void tf_core(uint32_t x0, uint32_t x1, uint32_t& o0, uint32_t& o1){
  const uint32_t k0 = 0u, k1 = 42u, k2 = 0u ^ 42u ^ 0x1BD11BDAu;
  x0 += k0; x1 += k1;
#define TF_R4(a,b,c,d) \
  x0+=x1; x1=rotl32(x1,a); x1^=x0; \
  x0+=x1; x1=rotl32(x1,b); x1^=x0; \
  x0+=x1; x1=rotl32(x1,c); x1^=x0; \
  x0+=x1; x1=rotl32(x1,d); x1^=x0;
  TF_R4(13,15,26,6)   x0+=k1; x1+=k2+1u;
  TF_R4(17,29,16,24)  x0+=k2; x1+=k0+2u;
  TF_R4(13,15,26,6)   x0+=k0; x1+=k1+3u;
  TF_R4(17,29,16,24)  x0+=k1; x1+=k2+4u;
  TF_R4(13,15,26,6)   x0+=k2; x1+=k0+5u;
#undef TF_R4
  o0 = x0; o1 = x1;
}

__device__ __forceinline__ uint32_t tf_bits(uint32_t j){
  uint32_t o0, o1;
  tf_core(0u, j, o0, o1);
  return o0 ^ o1;
}

// ---------------- pass 1: per-WG bucket counts, BOTH graphs ----------------
// cntMat layout is TRANSPOSED: [NB][NWG] so a wave per bucket can scan it.
__global__ __launch_bounds__(256) void pcountB_k(const int* __restrict__ socDst,
                                                 const int* __restrict__ coDst,
                                                 int chunkS, int chunkC,
                                                 int* __restrict__ cntMatS,
                                                 int* __restrict__ cntMatC){
  __shared__ int h[NB];
  int tid = threadIdx.x;
  bool isSoc = blockIdx.x < NWG;
  int wg = isSoc ? blockIdx.x : blockIdx.x - NWG;
  const int* dst = isSoc ? socDst : coDst;
  int E = isSoc ? E_SOC : E_CO;
  int chunk = isSoc ? chunkS : chunkC;
  int* cntMat = isSoc ? cntMatS : cntMatC;
  for (int i=tid; i<NB; i+=256) h[i]=0;
  __syncthreads();
  int lo = wg*chunk, hi = lo+chunk; if (hi > E) hi = E;
  for (int i=lo+tid; i<hi; i+=256) atomicAdd(&h[dst[i]>>8], 1);
  __syncthreads();
  for (int i=tid; i<NB; i+=256) cntMat[(size_t)i*NWG + wg] = h[i];
}

// ---------------- bucket totals: wave per bucket, both graphs ----------------
__global__ void btot2_k(const int* __restrict__ cntMatS, const int* __restrict__ cntMatC,
                        int* __restrict__ totS, int* __restrict__ totC){
  int g = (blockIdx.x*blockDim.x + threadIdx.x) >> 6;
  int lane = threadIdx.x & 63;
  if (g >= 2*NB) return;
  bool isSoc = g < NB;
  int b = isSoc ? g : g - NB;
  const int* row = (isSoc ? cntMatS : cntMatC) + (size_t)b*NWG;
  int s = row[lane*3] + row[lane*3+1] + row[lane*3+2];
  #pragma unroll
  for (int d=32; d; d>>=1) s += __shfl_xor(s, d, 64);
  if (lane == 0) (isSoc ? totS : totC)[b] = s;
}

// ---------------- scan bucket totals -> bbase (1 block per graph) ----------------
__global__ __launch_bounds__(1024) void bscan2_k(const int* __restrict__ totS, const int* __restrict__ totC,
                                                 int* __restrict__ bbaseS, int* __restrict__ bbaseC){
  __shared__ int sa[1024];
  int tid = threadIdx.x;
  const int* tot = blockIdx.x ? totC : totS;
  int* bbase     = blockIdx.x ? bbaseC : bbaseS;
  int E          = blockIdx.x ? E_CO   : E_SOC;
  int v = (tid < NB) ? tot[tid] : 0;
  sa[tid] = v;
  __syncthreads();
  for (int s=1; s<1024; s<<=1){
    int t = (tid>=s)?sa[tid-s]:0;
    __syncthreads();
    sa[tid] += t;
    __syncthreads();
  }
  if (tid < NB) bbase[tid] = sa[tid] - v;   // exclusive
  if (tid == 0) bbase[NB] = E;
}

// ---------------- per-(bucket,wg) start offsets: wave per bucket (shfl scan) ----------------
__global__ void wgpfx2_k(int* __restrict__ cntMatS, int* __restrict__ cntMatC,
                         const int* __restrict__ bbaseS, const int* __restrict__ bbaseC){
  int g = (blockIdx.x*blockDim.x + threadIdx.x) >> 6;
  int lane = threadIdx.x & 63;
  if (g >= 2*NB) return;
  bool isSoc = g < NB;
  int b = isSoc ? g : g - NB;
  int* row = (isSoc ? cntMatS : cntMatC) + (size_t)b*NWG;
  int base = (isSoc ? bbaseS : bbaseC)[b];
  int v0 = row[lane*3], v1 = row[lane*3+1], v2 = row[lane*3+2];
  int s = v0 + v1 + v2;
  int x = s;
  #pragma unroll
  for (int d=1; d<64; d<<=1){
    int t = __shfl_up(x, d, 64);
    if (lane >= d) x += t;
  }
  int excl = x - s;    // exclusive prefix of lane partials
  row[lane*3]   = base + excl;
  row[lane*3+1] = base + excl + v0;
  row[lane*3+2] = base + excl + v0 + v1;
}

// ---------------- pass 2: place records (LDS cursors, WG-private), both graphs ----------------
// soc record: u64 = (w_bits<<32) | (d_local<<18) | s ; co record: u32 = (d_local<<18) | s
__global__ __launch_bounds__(256) void pplaceB_k(const int* __restrict__ socSrc,
        const int* __restrict__ socDst, const float* __restrict__ socWgt,
        const int* __restrict__ coSrc,  const int* __restrict__ coDst,
        const int* __restrict__ cntMatS, const int* __restrict__ cntMatC,
        unsigned long long* __restrict__ recS, unsigned int* __restrict__ recC,
        int chunkS, int chunkC){
  __shared__ int curx[NB];
  int tid = threadIdx.x;
  bool isSoc = blockIdx.x < NWG;
  int wg = isSoc ? blockIdx.x : blockIdx.x - NWG;
  const int* offMat = isSoc ? cntMatS : cntMatC;
  for (int i=tid; i<NB; i+=256) curx[i] = offMat[(size_t)i*NWG + wg];
  __syncthreads();
  if (isSoc){
    int lo = wg*chunkS, hi = lo+chunkS; if (hi > E_SOC) hi = E_SOC;
    for (int i=lo+tid; i<hi; i+=256){
      int d = socDst[i];
      int p = atomicAdd(&curx[d>>8], 1);
      recS[p] = ((unsigned long long)__float_as_uint(socWgt[i])<<32)
              | (unsigned)(((d&255)<<18) | socSrc[i]);
    }
  } else {
    int lo = wg*chunkC, hi = lo+chunkC; if (hi > E_CO) hi = E_CO;
    for (int i=lo+tid; i<hi; i+=256){
      int d = coDst[i];
      int p = atomicAdd(&curx[d>>8], 1);
      recC[p] = (unsigned)(((d&255)<<18) | coSrc[i]);
    }
  }
}

// ---------------- bucket -> CSC, both graphs; folds alpha softmax (soc) and dinv (co) ----------------
__global__ __launch_bounds__(256) void cscB_k(const unsigned long long* __restrict__ recS,
    const unsigned int* __restrict__ recC,
    const int* __restrict__ bbaseS, const int* __restrict__ bbaseC,
    int* __restrict__ socOff, int* __restrict__ socSrcS, float* __restrict__ socWS,
    int* __restrict__ coOff, int* __restrict__ coSrcS, float* __restrict__ dinv){
  __shared__ int cnt[256], basex[256], curx[256];
  int tid = threadIdx.x;
  bool isSoc = blockIdx.x < NB;
  int b = isSoc ? blockIdx.x : blockIdx.x - NB;
  const int* bbase = isSoc ? bbaseS : bbaseC;
  int lo = bbase[b], hi = bbase[b+1];
  cnt[tid] = 0;
  __syncthreads();
  if (isSoc){
    for (int i = lo + tid; i < hi; i += 256)
      atomicAdd(&cnt[(((unsigned)recS[i]) >> 18) & 255], 1);
  } else {
    for (int i = lo + tid; i < hi; i += 256)
      atomicAdd(&cnt[(recC[i] >> 18) & 255], 1);
  }
  __syncthreads();
  int c = cnt[tid];
  basex[tid] = c; __syncthreads();
  for (int s=1; s<256; s<<=1){
    int t = (tid>=s)?basex[tid-s]:0; __syncthreads();
    basex[tid]+=t; __syncthreads();
  }
  int excl = basex[tid]-c;
  int node = b*256+tid;
  int* off = isSoc ? socOff : coOff;
  if (node <= NUM_TOTAL) off[node] = lo + excl;
  basex[tid] = excl; curx[tid] = 0;
  __syncthreads();
  if (isSoc){
    for (int i = lo + tid; i < hi; i += 256){
      unsigned long long r = recS[i];
      unsigned lw = (unsigned)r;
      int dl = (lw>>18)&255;
      int p = lo + basex[dl] + atomicAdd(&curx[dl],1);
      socSrcS[p] = lw & 0x3FFFF;
      socWS[p] = __uint_as_float((unsigned)(r>>32));
    }
    __syncthreads();
    // folded alpha softmax: this block owns ALL edges of its 256 nodes (L2-hot)
    if (node < NUM_TOTAL && c > 0){
      int e0 = lo + basex[tid], e1 = e0 + c;
      float m = -3.402823466e+38f;
      for (int e=e0; e<e1; ++e) m = fmaxf(m, socWS[e]);
      float s = 0.f;
      for (int e=e0; e<e1; ++e) s += expf(socWS[e] - m);
      float inv = 1.0f / (s + 1e-16f);
      for (int e=e0; e<e1; ++e) socWS[e] = expf(socWS[e] - m) * inv;
    }
  } else {
    for (int i = lo + tid; i < hi; i += 256){
      unsigned r = recC[i];
      int dl = (r>>18)&255;
      int p = lo + basex[dl] + atomicAdd(&curx[dl],1);
      coSrcS[p] = r & 0x3FFFF;
    }
    // folded dinv (deg = in-degree + self loop)
    if (node < NUM_TOTAL) dinv[node] = 1.0f / sqrtf((float)(c + 1));
  }
}

// ---------------- fused: negA threshold filter (VALU-bound) + f32->f16 conversion (stream-bound) ----
// Complementary pipes, light footprint on both sides (validated round 13; heavyweight variant
// taxing the memory-bound majority was a measured regression in round 14).
__global__ __launch_bounds__(256) void negAf2h_k(const int* __restrict__ user_items,
        unsigned long long* __restrict__ surv, int* __restrict__ scnt,
        const float4* __restrict__ fa, uint2* __restrict__ oa,
        const float4* __restrict__ fb, uint2* __restrict__ ob, int n4){
  __shared__ unsigned int mask[PMW];
  __shared__ int lcnt;
  int tid = threadIdx.x;
  if (blockIdx.x < BATCH*PARTS){
    int blk = blockIdx.x;
    int row = blk >> 2, part = blk & 3;
    int base = part * PIT;
    for (int i=tid; i<PMW; i+=256) mask[i] = 0u;
    if (tid == 0) lcnt = 0;
    __syncthreads();
    if (tid < MAX_UI){
      int it = user_items[row*MAX_UI + tid];
      if (it >= base && it < base + PIT){
        int li = it - base;
        atomicOr(&mask[li>>5], 1u << (li & 31));
      }
    }
    __syncthreads();
    unsigned jbase = (unsigned)row * 100000u + (unsigned)base;
    for (int k = tid; k < PIT; k += 1024){
      int i1 = k + 256, i2 = k + 512, i3 = k + 768;
      uint32_t b0 = tf_bits(jbase + (unsigned)k);
      uint32_t b1 = tf_bits(jbase + (unsigned)(i1 < PIT ? i1 : k));
      uint32_t b2 = tf_bits(jbase + (unsigned)(i2 < PIT ? i2 : k));
      uint32_t b3 = tf_bits(jbase + (unsigned)(i3 < PIT ? i3 : k));
      uint32_t v0 = b0 >> 9, v1 = b1 >> 9, v2 = b2 >> 9, v3 = b3 >> 9;
      if (v0 >= TH && !((mask[k>>5] >> (k&31)) & 1u)){
        int p = atomicAdd(&lcnt, 1);
        if (p < SCAP)
          surv[(size_t)blk*SCAP + p] = ((unsigned long long)v0 << 32) | (unsigned)(~(unsigned)(base + k));
      }
      if (i1 < PIT && v1 >= TH && !((mask[i1>>5] >> (i1&31)) & 1u)){
        int p = atomicAdd(&lcnt, 1);
        if (p < SCAP)
          surv[(size_t)blk*SCAP + p] = ((unsigned long long)v1 << 32) | (unsigned)(~(unsigned)(base + i1));
      }
      if (i2 < PIT && v2 >= TH && !((mask[i2>>5] >> (i2&31)) & 1u)){
        int p = atomicAdd(&lcnt, 1);
        if (p < SCAP)
          surv[(size_t)blk*SCAP + p] = ((unsigned long long)v2 << 32) | (unsigned)(~(unsigned)(base + i2));
      }
      if (i3 < PIT && v3 >= TH && !((mask[i3>>5] >> (i3&31)) & 1u)){
        int p = atomicAdd(&lcnt, 1);
        if (p < SCAP)
          surv[(size_t)blk*SCAP + p] = ((unsigned long long)v3 << 32) | (unsigned)(~(unsigned)(base + i3));
      }
    }
    __syncthreads();
    if (tid == 0) scnt[blk] = (lcnt < SCAP) ? lcnt : SCAP;
  } else {
    int i = (int)(blockIdx.x - BATCH*PARTS)*256 + tid;
    int st = 2048*256;
    for (; i<n4; i+=st){
      float4 va = fa[i], vb = fb[i];
      __half2 l = __float22half2_rn(make_float2(va.x,va.y));
      __half2 h = __float22half2_rn(make_float2(va.z,va.w));
      uint2 u; u.x = *(unsigned*)&l; u.y = *(unsigned*)&h;
      oa[i] = u;
      l = __float22half2_rn(make_float2(vb.x,vb.y));
      h = __float22half2_rn(make_float2(vb.z,vb.w));
      u.x = *(unsigned*)&l; u.y = *(unsigned*)&h;
      ob[i] = u;
    }
  }
}

// ---------------- aggregation: wave per dst node, f16 rows, 8-way MLP (separate kernels) ----------------
__global__ void agg_soc8_k(const __half2* __restrict__ x, __half2* __restrict__ y,
                           const int* __restrict__ off, const int* __restrict__ srcS,
                           const float* __restrict__ wE, int n){
  int gw = (blockIdx.x*blockDim.x + threadIdx.x) >> 6;
  int lane = threadIdx.x & 63;
  if (gw >= n) return;
  float ax = 0.f, ay = 0.f;
  int e = off[gw], e1 = off[gw+1];
  for (; e + 8 <= e1; e += 8){
    int s0=srcS[e],s1=srcS[e+1],s2=srcS[e+2],s3=srcS[e+3];
    int s4=srcS[e+4],s5=srcS[e+5],s6=srcS[e+6],s7=srcS[e+7];
    float a0=wE[e],a1=wE[e+1],a2=wE[e+2],a3=wE[e+3];
    float a4=wE[e+4],a5=wE[e+5],a6=wE[e+6],a7=wE[e+7];
    __half2 h0=x[(size_t)s0*64+lane], h1=x[(size_t)s1*64+lane];
    __half2 h2=x[(size_t)s2*64+lane], h3=x[(size_t)s3*64+lane];
    __half2 h4=x[(size_t)s4*64+lane], h5=x[(size_t)s5*64+lane];
    __half2 h6=x[(size_t)s6*64+lane], h7=x[(size_t)s7*64+lane];
    float2 f0=__half22float2(h0), f1=__half22float2(h1), f2=__half22float2(h2), f3=__half22float2(h3);
    float2 f4=__half22float2(h4), f5=__half22float2(h5), f6=__half22float2(h6), f7=__half22float2(h7);
    ax += a0*f0.x + a1*f1.x + a2*f2.x + a3*f3.x + a4*f4.x + a5*f5.x + a6*f6.x + a7*f7.x;
    ay += a0*f0.y + a1*f1.y + a2*f2.y + a3*f3.y + a4*f4.y + a5*f5.y + a6*f6.y + a7*f7.y;
  }
  for (; e < e1; ++e){
    int s = srcS[e]; float a = wE[e];
    float2 f = __half22float2(x[(size_t)s*64 + lane]);
    ax += a*f.x; ay += a*f.y;
  }
  y[(size_t)gw*64 + lane] = __float22half2_rn(make_float2(ax, ay));
}

__global__ void agg_co8_k(const __half2* __restrict__ x, __half2* __restrict__ y,
                          const int* __restrict__ off, const int* __restrict__ srcS,
                          const float* __restrict__ dinv, int n){
  int gw = (blockIdx.x*blockDim.x + threadIdx.x) >> 6;
  int lane = threadIdx.x & 63;
  if (gw >= n) return;
  float dv = dinv[gw];
  float2 fs = __half22float2(x[(size_t)gw*64 + lane]);
  float ax = dv*dv*fs.x, ay = dv*dv*fs.y;    // self-loop
  int e = off[gw], e1 = off[gw+1];
  for (; e + 8 <= e1; e += 8){
    int s0=srcS[e],s1=srcS[e+1],s2=srcS[e+2],s3=srcS[e+3];
    int s4=srcS[e+4],s5=srcS[e+5],s6=srcS[e+6],s7=srcS[e+7];
    float a0=dinv[s0]*dv,a1=dinv[s1]*dv,a2=dinv[s2]*dv,a3=dinv[s3]*dv;
    float a4=dinv[s4]*dv,a5=dinv[s5]*dv,a6=dinv[s6]*dv,a7=dinv[s7]*dv;
    __half2 h0=x[(size_t)s0*64+lane], h1=x[(size_t)s1*64+lane];
    __half2 h2=x[(size_t)s2*64+lane], h3=x[(size_t)s3*64+lane];
    __half2 h4=x[(size_t)s4*64+lane], h5=x[(size_t)s5*64+lane];
    __half2 h6=x[(size_t)s6*64+lane], h7=x[(size_t)s7*64+lane];
    float2 f0=__half22float2(h0), f1=__half22float2(h1), f2=__half22float2(h2), f3=__half22float2(h3);
    float2 f4=__half22float2(h4), f5=__half22float2(h5), f6=__half22float2(h6), f7=__half22float2(h7);
    ax += a0*f0.x + a1*f1.x + a2*f2.x + a3*f3.x + a4*f4.x + a5*f5.x + a6*f6.x + a7*f7.x;
    ay += a0*f0.y + a1*f1.y + a2*f2.y + a3*f3.y + a4*f4.y + a5*f5.y + a6*f6.y + a7*f7.y;
  }
  for (; e < e1; ++e){
    int s = srcS[e]; float a = dinv[s]*dv;
    float2 f = __half22float2(x[(size_t)s*64 + lane]);
    ax += a*f.x; ay += a*f.y;
  }
  y[(size_t)gw*64 + lane] = __float22half2_rn(make_float2(ax, ay));
}

// L2-normalize f16 rows in place (wave per row)
__global__ void norm_h_k(__half2* __restrict__ x, int n){
  int gw = (blockIdx.x*blockDim.x + threadIdx.x) >> 6;
  int lane = threadIdx.x & 63;
  if (gw >= n) return;
  __half2* p = x + (size_t)gw*64;
  float2 v = __half22float2(p[lane]);
  float ss = v.x*v.x + v.y*v.y;
  #pragma unroll
  for (int s=32; s; s>>=1) ss += __shfl_xor(ss, s, 64);
  float sc = 1.0f / fmaxf(sqrtf(ss), 1e-12f);
  p[lane] = __float22half2_rn(make_float2(v.x*sc, v.y*sc));
}

// fused: co-norm (150K waves) + anchor build+norm (100K waves) — 10-way static MLP
__global__ void postA_k(__half2* __restrict__ coE, const __half2* __restrict__ socE,
                        const int* __restrict__ item_users, __half2* __restrict__ anch){
  int gw = (blockIdx.x*blockDim.x + threadIdx.x) >> 6;
  int lane = threadIdx.x & 63;
  if (gw < NUM_TOTAL){
    __half2* p = coE + (size_t)gw*64;
    float2 v = __half22float2(p[lane]);
    float ss = v.x*v.x + v.y*v.y;
    #pragma unroll
    for (int s=32; s; s>>=1) ss += __shfl_xor(ss, s, 64);
    float sc = 1.0f / fmaxf(sqrtf(ss), 1e-12f);
    p[lane] = __float22half2_rn(make_float2(v.x*sc, v.y*sc));
  } else {
    int it = gw - NUM_TOTAL;
    if (it >= NUM_ITEM) return;
    const int* us = item_users + (size_t)it*MAX_IU;
    float ax = 0.f, ay = 0.f;
    for (int k=0; k<MAX_IU; k+=10){
      int u0=us[k],u1=us[k+1],u2=us[k+2],u3=us[k+3],u4=us[k+4];
      int u5=us[k+5],u6=us[k+6],u7=us[k+7],u8=us[k+8],u9=us[k+9];
      __half2 h0=socE[(size_t)u0*64+lane], h1=socE[(size_t)u1*64+lane];
      __half2 h2=socE[(size_t)u2*64+lane], h3=socE[(size_t)u3*64+lane];
      __half2 h4=socE[(size_t)u4*64+lane], h5=socE[(size_t)u5*64+lane];
      __half2 h6=socE[(size_t)u6*64+lane], h7=socE[(size_t)u7*64+lane];
      __half2 h8=socE[(size_t)u8*64+lane], h9=socE[(size_t)u9*64+lane];
      float2 f0=__half22float2(h0), f1=__half22float2(h1), f2=__half22float2(h2);
      float2 f3=__half22float2(h3), f4=__half22float2(h4), f5=__half22float2(h5);
      float2 f6=__half22float2(h6), f7=__half22float2(h7), f8=__half22float2(h8);
      float2 f9=__half22float2(h9);
      ax += f0.x+f1.x+f2.x+f3.x+f4.x+f5.x+f6.x+f7.x+f8.x+f9.x;
      ay += f0.y+f1.y+f2.y+f3.y+f4.y+f5.y+f6.y+f7.y+f8.y+f9.y;
    }
    const float inv = 1.0f / (50.0f + 1e-7f);
    ax *= inv; ay *= inv;
    float ss = ax*ax + ay*ay;
    #pragma unroll
    for (int s=32; s; s>>=1) ss += __shfl_xor(ss, s, 64);
    float sc = 1.0f / fmaxf(sqrtf(ss), 1e-12f);
    anch[(size_t)it*64 + lane] = __float22half2_rn(make_float2(ax*sc, ay*sc));
  }
}

// ---------------- negatives: phase B — merge survivors, exact top-10 ----------------
__global__ __launch_bounds__(256) void negB_k(const unsigned long long* __restrict__ surv,
                                              const int* __restrict__ scnt,
                                              const int* __restrict__ user_items,
                                              const int* __restrict__ n_id,
                                              int* __restrict__ cand){
  __shared__ unsigned long long keys[PARTS*SCAP];
  __shared__ unsigned long long red[256];
  __shared__ int cnts[PARTS];
  __shared__ int uix[MAX_UI];
  int b = blockIdx.x, tid = threadIdx.x;
  if (tid < PARTS) cnts[tid] = scnt[b*PARTS + tid];
  for (int i=tid; i<PARTS*SCAP; i+=256) keys[i] = 0ull;
  __syncthreads();
  int o0 = 0, o1 = cnts[0], o2 = o1 + cnts[1], o3 = o2 + cnts[2];
  int total = o3 + cnts[3];
  if (tid < cnts[0]) keys[o0 + tid] = surv[(size_t)(b*PARTS+0)*SCAP + tid];
  if (tid < cnts[1]) keys[o1 + tid] = surv[(size_t)(b*PARTS+1)*SCAP + tid];
  if (tid < cnts[2]) keys[o2 + tid] = surv[(size_t)(b*PARTS+2)*SCAP + tid];
  if (tid < cnts[3]) keys[o3 + tid] = surv[(size_t)(b*PARTS+3)*SCAP + tid];
  __syncthreads();
  if (total >= 10){
    for (int r=0; r<10; ++r){
      unsigned long long m = 0ull;
      for (int i=tid; i<PARTS*SCAP; i+=256){ unsigned long long v = keys[i]; if (v > m) m = v; }
      red[tid] = m; __syncthreads();
      for (int s=128; s>0; s>>=1){
        if (tid < s && red[tid+s] > red[tid]) red[tid] = red[tid+s];
        __syncthreads();
      }
      unsigned long long win = red[0];
      if (tid == 0)
        cand[b*NCAND + 1 + r] = NUM_USER + (int)(~(unsigned)(win & 0xffffffffull));
      for (int i=tid; i<PARTS*SCAP; i+=256) if (keys[i] == win) keys[i] = 0ull;
      __syncthreads();
    }
  } else {
    // deterministic exact slow path (probability ~e^-100; never taken in practice)
    if (tid < MAX_UI) uix[tid] = user_items[b*MAX_UI + tid];
    __syncthreads();
    unsigned long long prev = ~0ull;
    for (int r=0; r<10; ++r){
      unsigned long long m = 0ull;
      for (int i=tid; i<NUM_ITEM; i+=256){
        bool msk = false;
        for (int j=0; j<MAX_UI; ++j) if (uix[j] == i) msk = true;
        if (msk) continue;
        uint32_t v = tf_bits((unsigned)b*100000u + (unsigned)i) >> 9;
        unsigned long long key = ((unsigned long long)v << 32) | (unsigned)(~(unsigned)i);
        if (key < prev && key > m) m = key;
      }
      red[tid] = m; __syncthreads();
      for (int s=128; s>0; s>>=1){
        if (tid < s && red[tid+s] > red[tid]) red[tid] = red[tid+s];
        __syncthreads();
      }
      unsigned long long win = red[0];
      prev = win;
      if (tid == 0)
        cand[b*NCAND + 1 + r] = NUM_USER + (int)(~(unsigned)(win & 0xffffffffull));
      __syncthreads();
    }
  }
  if (tid == 0) cand[b*NCAND] = n_id[b*2 + 1];   // positive item (global id)
}

// ---------------- similarity (mean over walks collapses to one dot), f16 rows ----------------
__global__ void sim_h_k(const __half2* __restrict__ coN, const __half2* __restrict__ socU,
                        const __half2* __restrict__ socI, const int* __restrict__ cand,
                        const int* __restrict__ walks, float* __restrict__ out){
  int b = blockIdx.x;
  int lane = threadIdx.x;   // 64 threads
  float scx=0.f, scy=0.f, ssx=0.f, ssy=0.f;
  for (int w=0; w<NWALK; w+=4){
    int i0 = walks[b*NWALK + w],   i1 = walks[b*NWALK + w+1];
    int i2 = walks[b*NWALK + w+2], i3 = walks[b*NWALK + w+3];
    __half2 c0 = coN[(size_t)i0*64 + lane], c1 = coN[(size_t)i1*64 + lane];
    __half2 c2 = coN[(size_t)i2*64 + lane], c3 = coN[(size_t)i3*64 + lane];
    const __half2* p0 = (i0 < NUM_USER) ? socU + (size_t)i0*64 : socI + (size_t)(i0-NUM_USER)*64;
    const __half2* p1 = (i1 < NUM_USER) ? socU + (size_t)i1*64 : socI + (size_t)(i1-NUM_USER)*64;
    const __half2* p2 = (i2 < NUM_USER) ? socU + (size_t)i2*64 : socI + (size_t)(i2-NUM_USER)*64;
    const __half2* p3 = (i3 < NUM_USER) ? socU + (size_t)i3*64 : socI + (size_t)(i3-NUM_USER)*64;
    __half2 s0 = p0[lane], s1 = p1[lane], s2 = p2[lane], s3 = p3[lane];
    float2 fc0 = __half22float2(c0), fc1 = __half22float2(c1);
    float2 fc2 = __half22float2(c2), fc3 = __half22float2(c3);
    float2 fs0 = __half22float2(s0), fs1 = __half22float2(s1);
    float2 fs2 = __half22float2(s2), fs3 = __half22float2(s3);
    scx += fc0.x + fc1.x + fc2.x + fc3.x;
    scy += fc0.y + fc1.y + fc2.y + fc3.y;
    ssx += fs0.x + fs1.x + fs2.x + fs3.x;
    ssy += fs0.y + fs1.y + fs2.y + fs3.y;
  }
  for (int c=0; c<NCAND; ++c){
    int idx = cand[b*NCAND + c];                 // always in [NUM_USER, NUM_TOTAL)
    float2 cv = __half22float2(coN[(size_t)idx*64 + lane]);
    float2 sv = __half22float2(socI[(size_t)(idx - NUM_USER)*64 + lane]);
    float dco = cv.x*scx + cv.y*scy;
    float dso = sv.x*ssx + sv.y*ssy;
    #pragma unroll
    for (int s=32; s; s>>=1){
      dco += __shfl_xor(dco, s, 64);
      dso += __shfl_xor(dso, s, 64);
    }
    if (lane == 0){
      float com = 0.5f + 0.5f*(dco / 96.0f);
      float som = 0.5f + 0.5f*(dso / 96.0f);
      out[b*NCAND + c] = 0.7f*com + 0.3f*som;
    }
  }
}

// ---------------- host ----------------
extern "C" void kernel_launch(void* const* d_in, const int* in_sizes, int n_in,
                              void* d_out, int out_size, void* d_ws, size_t ws_size,
                              hipStream_t stream){
  (void)in_sizes; (void)n_in; (void)out_size; (void)ws_size;
  const float* id_emb     = (const float*)d_in[0];
  const float* soc_id_emb = (const float*)d_in[1];
  const float* soc_w      = (const float*)d_in[2];
  const int*   soc_ei     = (const int*)d_in[3];   // [0:E) src, [E:2E) dst
  const int*   co_ei      = (const int*)d_in[4];
  const int*   n_id       = (const int*)d_in[5];
  const int*   user_items = (const int*)d_in[6];
  const int*   item_users = (const int*)d_in[7];
  const int*   walks      = (const int*)d_in[8];
  float* out = (float*)d_out;

  // workspace layout (~225 MB; records aliased into t16, anchors into socId16)
  char* w = (char*)d_ws;
  size_t cur = 0;
  auto take = [&](size_t bytes)->void*{
    void* p = w + cur;
    cur = (cur + bytes + 255) & ~(size_t)255;
    return p;
  };
  __half2* socId16 = (__half2*)take((size_t)NUM_TOTAL*64*4);   // f16 soc_id_emb; later reused as anch16
  __half2* id16    = (__half2*)take((size_t)NUM_TOTAL*64*4);   // f16 id_emb; layer-2 co output
  __half2* t16     = (__half2*)take((size_t)NUM_TOTAL*64*4);   // rec buffers now, layer-2 soc output later
  __half2* soc16   = (__half2*)take((size_t)NUM_TOTAL*64*4);   // layer-1 soc output
  __half2* co16    = (__half2*)take((size_t)NUM_TOTAL*64*4);   // layer-1 co output
  int*   socOff  = (int*)take((size_t)(NUM_TOTAL+1)*4);
  int*   coOff   = (int*)take((size_t)(NUM_TOTAL+1)*4);
  float* dinv    = (float*)take((size_t)NUM_TOTAL*4);
  int*   socSrcS = (int*)take((size_t)E_SOC*4);
  float* socWS   = (float*)take((size_t)E_SOC*4);
  int*   coSrcS  = (int*)take((size_t)E_CO*4);
  int*   cntMatS = (int*)take((size_t)NWG*NB*4);   // layout [NB][NWG]
  int*   cntMatC = (int*)take((size_t)NWG*NB*4);   // layout [NB][NWG]
  int*   bbaseS  = (int*)take((size_t)(NB+1)*4);
  int*   bbaseC  = (int*)take((size_t)(NB+1)*4);
  int*   totS    = (int*)take((size_t)NB*4);
  int*   totC    = (int*)take((size_t)NB*4);
  unsigned long long* surv = (unsigned long long*)take((size_t)BATCH*PARTS*SCAP*8);
  int*   scnt    = (int*)take((size_t)BATCH*PARTS*4);
  int*   cand    = (int*)take((size_t)BATCH*NCAND*4);

  // records aliased into t16's 38.4 MB (dead until layer-2 agg writes t16):
  unsigned long long* recS = (unsigned long long*)t16;                        // 12.8 MB
  unsigned int*       recC = (unsigned int*)((char*)t16 + (size_t)E_SOC*8);   // 12.8 MB

  __half2* anch16 = socId16;   // socId16 dead after layer-1 agg

  const int T = 256;
  const int chunkS = (E_SOC + NWG - 1) / NWG;   // 8334
  const int chunkC = (E_CO  + NWG - 1) / NWG;   // 16667

  // ---- CSC build: contention-free two-pass counting partition (both graphs fused) ----
  pcountB_k<<<2*NWG, T, 0, stream>>>(soc_ei + E_SOC, co_ei + E_CO, chunkS, chunkC, cntMatS, cntMatC);
  int scanGrid = (2*NB*64 + T - 1) / T;   // wave per bucket
  btot2_k<<<scanGrid, T, 0, stream>>>(cntMatS, cntMatC, totS, totC);
  bscan2_k<<<2, 1024, 0, stream>>>(totS, totC, bbaseS, bbaseC);
  wgpfx2_k<<<scanGrid, T, 0, stream>>>(cntMatS, cntMatC, bbaseS, bbaseC);
  pplaceB_k<<<2*NWG, T, 0, stream>>>(soc_ei, soc_ei + E_SOC, soc_w,
                                     co_ei, co_ei + E_CO,
                                     cntMatS, cntMatC, recS, recC, chunkS, chunkC);
  cscB_k<<<2*NB, T, 0, stream>>>(recS, recC, bbaseS, bbaseC,
                                 socOff, socSrcS, socWS, coOff, coSrcS, dinv);

  // ---- fused negA (VALU) + f32->f16 conversion (stream) ----
  negAf2h_k<<<BATCH*PARTS + 2048, T, 0, stream>>>(user_items, surv, scnt,
                                 (const float4*)soc_id_emb, (uint2*)socId16,
                                 (const float4*)id_emb,     (uint2*)id16, NUM_TOTAL*32);

  // ---- graph convolutions (separate kernels: one gather table live per dispatch) ----
  int aggGrid = (NUM_TOTAL + 3) / 4;
  agg_soc8_k<<<aggGrid, T, 0, stream>>>(socId16, soc16, socOff, socSrcS, socWS, NUM_TOTAL); // layer1 -> soc16
  agg_soc8_k<<<aggGrid, T, 0, stream>>>(soc16,   t16,   socOff, socSrcS, socWS, NUM_TOTAL); // layer2 -> t16 (recs dead)
  agg_co8_k <<<aggGrid, T, 0, stream>>>(id16,    co16,  coOff,  coSrcS,  dinv,  NUM_TOTAL); // layer1 -> co16
  agg_co8_k <<<aggGrid, T, 0, stream>>>(co16,    id16,  coOff,  coSrcS,  dinv,  NUM_TOTAL); // layer2 -> id16

  // final locations: soc_emb = t16, co_emb = id16
  __half2* socE = t16;
  __half2* coE  = id16;

  // ---- fused co-norm + anchors (anchor reads UNnormalized soc rows) ----
  postA_k<<<(2*NUM_TOTAL - NUM_USER + 3)/4, T, 0, stream>>>(coE, socE, item_users, anch16);
  norm_h_k<<<(NUM_USER + 3)/4, T, 0, stream>>>(socE, NUM_USER);   // soc_n users

  // ---- negatives phase B + final similarity ----
  negB_k<<<BATCH, T, 0, stream>>>(surv, scnt, user_items, n_id, cand);
  sim_h_k<<<BATCH, 64, 0, stream>>>(coE, socE, anch16, cand, walks, out);
}